// Round 1
// baseline (929.935 us; speedup 1.0000x reference)
//
#include <hip/hip_runtime.h>
#include <hip/hip_bf16.h>
#include <math.h>

#define NB    4
#define NTOK  8192
#define DIM   1024
#define HDIM  512
#define NKEEP 4096

// ---------------------------------------------------------------------------
// Kernel A: fused scorer  scores[g] = W2 . gelu(tokens[g] @ W1 + b1) + b2
// grid 512 blocks (64 tokens each), 512 threads (8 waves).
// Wave w computes tokens t0=w*8..w*8+7; lane jg covers j = jg*8..jg*8+7.
// Double-buffered LDS tiles, fp32 VALU FMA (no fp32 MFMA on CDNA4).
// ---------------------------------------------------------------------------
#define TM 64
#define KC 16
#define NCHUNK (DIM / KC)

__global__ __launch_bounds__(512, 4)
void dtr_scores_kernel(const float* __restrict__ tokens,
                       const float* __restrict__ W1,
                       const float* __restrict__ b1,
                       const float* __restrict__ W2,
                       const float* __restrict__ b2,
                       float* __restrict__ scores)
{
    // A stored transposed [k][t] (pad 68 keeps rows 16B-aligned, 2-way max conflict)
    __shared__ float As[2][KC][TM + 4];
    __shared__ float Bs[2][KC][HDIM + 4];

    const int tid   = threadIdx.x;
    const int wave  = tid >> 6;
    const int lane  = tid & 63;
    const int gtok0 = blockIdx.x * TM;   // flat token row base (batch folded in)
    const int j0    = lane * 8;

    float w2v[8], b1v[8];
#pragma unroll
    for (int jj = 0; jj < 8; ++jj) {
        w2v[jj] = W2[j0 + jj];
        b1v[jj] = b1[j0 + jj];
    }

    float acc[8][8];
#pragma unroll
    for (int i = 0; i < 8; ++i)
#pragma unroll
        for (int jj = 0; jj < 8; ++jj) acc[i][jj] = 0.0f;

    auto stage = [&](int buf, int c) {
        const int k0 = c * KC;
        if (tid < 256) {
            // A tile: 64 tok x 16 k = 1024 floats; thread -> one float4 along k
            const int t  = tid >> 2;
            const int kk = (tid & 3) * 4;
            const float4 v = *reinterpret_cast<const float4*>(
                &tokens[(size_t)(gtok0 + t) * DIM + k0 + kk]);
            As[buf][kk + 0][t] = v.x;
            As[buf][kk + 1][t] = v.y;
            As[buf][kk + 2][t] = v.z;
            As[buf][kk + 3][t] = v.w;
        } else {
            // B tile: 16 k x 512 j = 8192 floats; 256 threads x 8 float4
            const int id = tid - 256;
#pragma unroll
            for (int p = 0; p < 8; ++p) {
                const int idx = id + p * 256;
                const int row = idx >> 7;
                const int c4  = (idx & 127) * 4;
                const float4 v = *reinterpret_cast<const float4*>(
                    &W1[(size_t)(k0 + row) * HDIM + c4]);
                *reinterpret_cast<float4*>(&Bs[buf][row][c4]) = v;
            }
        }
    };

    stage(0, 0);
    __syncthreads();

    int buf = 0;
    const int t0 = wave * 8;
    for (int c = 0; c < NCHUNK; ++c) {
        if (c + 1 < NCHUNK) stage(buf ^ 1, c + 1);
#pragma unroll
        for (int kk = 0; kk < KC; ++kk) {
            const float4 a0  = *reinterpret_cast<const float4*>(&As[buf][kk][t0]);
            const float4 a1  = *reinterpret_cast<const float4*>(&As[buf][kk][t0 + 4]);
            const float4 bv0 = *reinterpret_cast<const float4*>(&Bs[buf][kk][j0]);
            const float4 bv1 = *reinterpret_cast<const float4*>(&Bs[buf][kk][j0 + 4]);
            const float a[8]  = {a0.x, a0.y, a0.z, a0.w, a1.x, a1.y, a1.z, a1.w};
            const float bb[8] = {bv0.x, bv0.y, bv0.z, bv0.w, bv1.x, bv1.y, bv1.z, bv1.w};
#pragma unroll
            for (int i = 0; i < 8; ++i)
#pragma unroll
                for (int jj = 0; jj < 8; ++jj)
                    acc[i][jj] = fmaf(a[i], bb[jj], acc[i][jj]);
        }
        __syncthreads();
        buf ^= 1;
    }

    // Epilogue: exact GELU + dot with W2, then 64-lane reduce (j fully in-wave)
    float ssum[8];
#pragma unroll
    for (int i = 0; i < 8; ++i) {
        float s = 0.0f;
#pragma unroll
        for (int jj = 0; jj < 8; ++jj) {
            const float h = acc[i][jj] + b1v[jj];
            const float g = 0.5f * h * (1.0f + erff(h * 0.70710678118654752f));
            s = fmaf(g, w2v[jj], s);
        }
        ssum[i] = s;
    }
#pragma unroll
    for (int i = 0; i < 8; ++i) {
#pragma unroll
        for (int off = 32; off > 0; off >>= 1)
            ssum[i] += __shfl_xor(ssum[i], off, 64);
    }
    if (lane == 0) {
        const float bias2 = b2[0];
#pragma unroll
        for (int i = 0; i < 8; ++i)
            scores[gtok0 + t0 + i] = ssum[i] + bias2;
    }
}

// ---------------------------------------------------------------------------
// Block-wide exclusive scan (1024 threads, one int per thread). lds >= 16 ints.
// ---------------------------------------------------------------------------
__device__ __forceinline__ int blk_excl_scan_1024(int v, int tid, int* lds, int* tot)
{
    const int lane = tid & 63;
    const int wid  = tid >> 6;
    int x = v;
#pragma unroll
    for (int d = 1; d < 64; d <<= 1) {
        const int y = __shfl_up(x, d, 64);
        if (lane >= d) x += y;
    }
    if (lane == 63) lds[wid] = x;          // inclusive wave sums
    __syncthreads();
    if (wid == 0) {
        int w = (lane < 16) ? lds[lane] : 0;
#pragma unroll
        for (int d = 1; d < 16; d <<= 1) {
            const int y = __shfl_up(w, d, 64);
            if (lane >= d) w += y;
        }
        if (lane < 16) lds[lane] = w;      // inclusive scanned wave sums
    }
    __syncthreads();
    const int wave_off = (wid == 0) ? 0 : lds[wid - 1];
    const int total    = lds[15];
    __syncthreads();                       // lds reusable after return
    *tot = total;
    return wave_off + x - v;               // exclusive prefix
}

// ---------------------------------------------------------------------------
// Kernel B: exact top-k per batch. Bitonic-sort a copy of scores in LDS to get
// the threshold (4096th largest), tie-break by lowest index (matches
// jax.lax.top_k + sort(indices)), emit sorted compacted indices + 0/1 mask.
// ---------------------------------------------------------------------------
__global__ __launch_bounds__(1024)
void dtr_topk_kernel(const float* __restrict__ scores,
                     int* __restrict__ idx_out,
                     float* __restrict__ mask_out)
{
    __shared__ float sv[NTOK];   // 32 KB
    __shared__ int scan_lds[16];

    const int b   = blockIdx.x;
    const int tid = threadIdx.x;
    const float* s = scores + (size_t)b * NTOK;

    for (int i = tid; i < NTOK; i += 1024) sv[i] = s[i];
    __syncthreads();

    // bitonic sort ascending
    for (int k = 2; k <= NTOK; k <<= 1) {
        for (int j = k >> 1; j > 0; j >>= 1) {
            for (int i = tid; i < NTOK; i += 1024) {
                const int ixj = i ^ j;
                if (ixj > i) {
                    const float av = sv[i];
                    const float bv = sv[ixj];
                    const bool asc = ((i & k) == 0);
                    if ((av > bv) == asc) { sv[i] = bv; sv[ixj] = av; }
                }
            }
            __syncthreads();
        }
    }

    const float T = sv[NTOK - NKEEP];   // 4096th largest (ascending pos 4096)

    const int i0 = tid * 8;
    float sc[8];
#pragma unroll
    for (int q = 0; q < 8; ++q) sc[q] = s[i0 + q];

    int sum_g = 0, sum_e = 0;
#pragma unroll
    for (int q = 0; q < 8; ++q) {
        sum_g += (sc[q] > T) ? 1 : 0;
        sum_e += (sc[q] == T) ? 1 : 0;
    }
    int tot_g, tot_e;
    (void)blk_excl_scan_1024(sum_g, tid, scan_lds, &tot_g);
    const int off_e = blk_excl_scan_1024(sum_e, tid, scan_lds, &tot_e);

    const int need = NKEEP - tot_g;     // how many ==T to keep (lowest index first)

    int keep[8];
    int sum_k = 0;
    int er = off_e;
#pragma unroll
    for (int q = 0; q < 8; ++q) {
        int kf = 0;
        if (sc[q] > T) kf = 1;
        else if (sc[q] == T) { kf = (er < need) ? 1 : 0; ++er; }
        keep[q] = kf;
        sum_k += kf;
    }
    int tot_k;
    int pos = blk_excl_scan_1024(sum_k, tid, scan_lds, &tot_k);

#pragma unroll
    for (int q = 0; q < 8; ++q) {
        mask_out[(size_t)b * NTOK + i0 + q] = keep[q] ? 1.0f : 0.0f;
        if (keep[q]) {
            idx_out[(size_t)b * NKEEP + pos] = i0 + q;
            ++pos;
        }
    }
}

// ---------------------------------------------------------------------------
// Kernel C: gather selected token rows. One block per (b, kpos): 1024 floats.
// ---------------------------------------------------------------------------
__global__ __launch_bounds__(256)
void dtr_gather_kernel(const float* __restrict__ tokens,
                       const int* __restrict__ idx,
                       float* __restrict__ selected)
{
    const int g    = blockIdx.x;        // 0 .. NB*NKEEP-1
    const int b    = g >> 12;           // / NKEEP
    const int src  = idx[g];
    const float4* sp = reinterpret_cast<const float4*>(
        tokens + ((size_t)b * NTOK + (size_t)src) * DIM);
    float4* dp = reinterpret_cast<float4*>(selected + (size_t)g * DIM);
    dp[threadIdx.x] = sp[threadIdx.x];
}

// ---------------------------------------------------------------------------
extern "C" void kernel_launch(void* const* d_in, const int* in_sizes, int n_in,
                              void* d_out, int out_size, void* d_ws, size_t ws_size,
                              hipStream_t stream)
{
    const float* tokens = (const float*)d_in[0];  // [4,8192,1024]
    const float* W1     = (const float*)d_in[1];  // [1024,512]
    const float* b1     = (const float*)d_in[2];  // [512]
    const float* W2     = (const float*)d_in[3];  // [512,1]
    const float* b2     = (const float*)d_in[4];  // [1]

    float* out      = (float*)d_out;
    float* selected = out;                                   // 4*4096*1024
    float* mask     = out + (size_t)NB * NKEEP * DIM;        // 4*8192

    float* scores = (float*)d_ws;                            // 32768 f32
    int*   idx    = (int*)((char*)d_ws + (size_t)NB * NTOK * sizeof(float));

    dtr_scores_kernel<<<(NB * NTOK) / TM, 512, 0, stream>>>(
        tokens, W1, b1, W2, b2, scores);
    dtr_topk_kernel<<<NB, 1024, 0, stream>>>(scores, idx, mask);
    dtr_gather_kernel<<<NB * NKEEP, 256, 0, stream>>>(tokens, idx, selected);
}

// Round 2
// 579.872 us; speedup vs baseline: 1.6037x; 1.6037x over previous
//
#include <hip/hip_runtime.h>
#include <hip/hip_bf16.h>
#include <math.h>

#define NB    4
#define NTOK  8192
#define DIM   1024
#define HDIM  512
#define NKEEP 4096

// ---------------------------------------------------------------------------
// Kernel A: fused scorer  scores[g] = W2 . gelu(tokens[g] @ W1 + b1) + b2
// 256 blocks (128 tokens each, 1 block/CU), 512 threads (8 waves).
// Wave w owns tokens t0=w*16..w*16+15 (A reads are wave-uniform -> broadcast).
// Lane owns j in {lane*4..+3} u {256+lane*4..+3} (B reads lane*16B contiguous,
// conflict-free). Both tiles staged via global_load_lds (width 16, linear LDS).
// fp32 VALU FMA (no fp32 MFMA on CDNA4; bf16-split too imprecise for top-k).
// ---------------------------------------------------------------------------
#define TM  128
#define KC  16
#define NCHUNK (DIM / KC)
#define TPW 16

#define GLD16(g, s) __builtin_amdgcn_global_load_lds(                       \
    (const __attribute__((address_space(1))) void*)(g),                    \
    (__attribute__((address_space(3))) void*)(s), 16, 0, 0)

__global__ __launch_bounds__(512, 2)
void dtr_scores_kernel(const float* __restrict__ tokens,
                       const float* __restrict__ W1,
                       const float* __restrict__ b1g,
                       const float* __restrict__ W2,
                       const float* __restrict__ b2g,
                       float* __restrict__ scores)
{
    __shared__ __align__(16) float As[2][TM][KC];    // 8 KB per buf, [t][k]
    __shared__ __align__(16) float Bs[2][KC][HDIM];  // 32 KB per buf, [k][j]

    const int tid   = threadIdx.x;
    const int wid   = tid >> 6;
    const int lane  = tid & 63;
    const int gtok0 = blockIdx.x * TM;
    const int t0    = wid * TPW;
    const int j0    = lane * 4;

    float acc[TPW][8];
#pragma unroll
    for (int i = 0; i < TPW; ++i)
#pragma unroll
        for (int jj = 0; jj < 8; ++jj) acc[i][jj] = 0.0f;

    // --- async staging: chunk c -> buffer buf (all loads land at barrier) ---
    auto stage = [&](int buf, int c) {
        const int k0 = c * KC;
        {   // A tile: 128 tok x 16 k = 8 KB; thread -> 16B (t=tid/4, ko=(tid%4)*4)
            const int t  = tid >> 2;
            const int ko = (tid & 3) * 4;
            GLD16(&tokens[(size_t)(gtok0 + t) * DIM + k0 + ko], &As[buf][t][ko]);
        }
        {   // B tile: rows k0..k0+15 of W1 are 32 KB contiguous
            const float* gb = W1 + (size_t)k0 * HDIM;
            float* sb = &Bs[buf][0][0];
#pragma unroll
            for (int p = 0; p < 4; ++p) {
                const int f = tid * 4 + p * 2048;   // float index, = byte/4
                GLD16(gb + f, sb + f);
            }
        }
    };

    stage(0, 0);
    __syncthreads();

    int buf = 0;
    for (int c = 0; c < NCHUNK; ++c) {
        if (c + 1 < NCHUNK) stage(buf ^ 1, c + 1);

#pragma unroll
        for (int kq = 0; kq < 4; ++kq) {
            // B fragments for 4 consecutive k (lane*16B reads: conflict-free)
            float4 bl[4], bh[4];
#pragma unroll
            for (int q = 0; q < 4; ++q) {
                bl[q] = *reinterpret_cast<const float4*>(&Bs[buf][kq * 4 + q][j0]);
                bh[q] = *reinterpret_cast<const float4*>(&Bs[buf][kq * 4 + q][256 + j0]);
            }
#pragma unroll
            for (int h = 0; h < 2; ++h) {
                // A fragments: 8 tokens x 4 k, wave-uniform address (broadcast)
                float4 a[8];
#pragma unroll
                for (int i = 0; i < 8; ++i)
                    a[i] = *reinterpret_cast<const float4*>(&As[buf][t0 + h * 8 + i][kq * 4]);
#pragma unroll
                for (int i = 0; i < 8; ++i) {
                    const float av[4] = {a[i].x, a[i].y, a[i].z, a[i].w};
                    float* A8 = acc[h * 8 + i];
#pragma unroll
                    for (int q = 0; q < 4; ++q) {
                        A8[0] = fmaf(av[q], bl[q].x, A8[0]);
                        A8[1] = fmaf(av[q], bl[q].y, A8[1]);
                        A8[2] = fmaf(av[q], bl[q].z, A8[2]);
                        A8[3] = fmaf(av[q], bl[q].w, A8[3]);
                        A8[4] = fmaf(av[q], bh[q].x, A8[4]);
                        A8[5] = fmaf(av[q], bh[q].y, A8[5]);
                        A8[6] = fmaf(av[q], bh[q].z, A8[6]);
                        A8[7] = fmaf(av[q], bh[q].w, A8[7]);
                    }
                }
            }
        }
        __syncthreads();
        buf ^= 1;
    }

    // --- epilogue: exact GELU + W2 dot, 64-lane butterfly reduce per token ---
    const float4 w2a = *reinterpret_cast<const float4*>(&W2[j0]);
    const float4 w2b = *reinterpret_cast<const float4*>(&W2[256 + j0]);
    const float4 b1a = *reinterpret_cast<const float4*>(&b1g[j0]);
    const float4 b1b = *reinterpret_cast<const float4*>(&b1g[256 + j0]);
    const float ww[8] = {w2a.x, w2a.y, w2a.z, w2a.w, w2b.x, w2b.y, w2b.z, w2b.w};
    const float bb[8] = {b1a.x, b1a.y, b1a.z, b1a.w, b1b.x, b1b.y, b1b.z, b1b.w};

    const float bias2 = b2g[0];
#pragma unroll
    for (int i = 0; i < TPW; ++i) {
        float s = 0.0f;
#pragma unroll
        for (int jj = 0; jj < 8; ++jj) {
            const float h = acc[i][jj] + bb[jj];
            const float g = 0.5f * h * (1.0f + erff(h * 0.70710678118654752f));
            s = fmaf(g, ww[jj], s);
        }
#pragma unroll
        for (int off = 32; off > 0; off >>= 1)
            s += __shfl_xor(s, off, 64);
        if (lane == 0) scores[gtok0 + t0 + i] = s + bias2;
    }
}

// ---------------------------------------------------------------------------
// Block-wide exclusive scan (1024 threads, one int per thread). lds >= 16 ints.
// ---------------------------------------------------------------------------
__device__ __forceinline__ int blk_excl_scan_1024(int v, int tid, int* lds, int* tot)
{
    const int lane = tid & 63;
    const int wid  = tid >> 6;
    int x = v;
#pragma unroll
    for (int d = 1; d < 64; d <<= 1) {
        const int y = __shfl_up(x, d, 64);
        if (lane >= d) x += y;
    }
    if (lane == 63) lds[wid] = x;          // inclusive wave sums
    __syncthreads();
    if (wid == 0) {
        int w = (lane < 16) ? lds[lane] : 0;
#pragma unroll
        for (int d = 1; d < 16; d <<= 1) {
            const int y = __shfl_up(w, d, 64);
            if (lane >= d) w += y;
        }
        if (lane < 16) lds[lane] = w;      // inclusive scanned wave sums
    }
    __syncthreads();
    const int wave_off = (wid == 0) ? 0 : lds[wid - 1];
    const int total    = lds[15];
    __syncthreads();                       // lds reusable after return
    *tot = total;
    return wave_off + x - v;               // exclusive prefix
}

// ---------------------------------------------------------------------------
// Kernel B: exact top-k per batch. Bitonic-sort a copy of scores in LDS to get
// the threshold (4096th largest), tie-break by lowest index (matches
// jax.lax.top_k + sort(indices)), emit sorted compacted indices + 0/1 mask.
// ---------------------------------------------------------------------------
__global__ __launch_bounds__(1024)
void dtr_topk_kernel(const float* __restrict__ scores,
                     int* __restrict__ idx_out,
                     float* __restrict__ mask_out)
{
    __shared__ float sv[NTOK];   // 32 KB
    __shared__ int scan_lds[16];

    const int b   = blockIdx.x;
    const int tid = threadIdx.x;
    const float* s = scores + (size_t)b * NTOK;

    for (int i = tid; i < NTOK; i += 1024) sv[i] = s[i];
    __syncthreads();

    // bitonic sort ascending
    for (int k = 2; k <= NTOK; k <<= 1) {
        for (int j = k >> 1; j > 0; j >>= 1) {
            for (int i = tid; i < NTOK; i += 1024) {
                const int ixj = i ^ j;
                if (ixj > i) {
                    const float av = sv[i];
                    const float bv = sv[ixj];
                    const bool asc = ((i & k) == 0);
                    if ((av > bv) == asc) { sv[i] = bv; sv[ixj] = av; }
                }
            }
            __syncthreads();
        }
    }

    const float T = sv[NTOK - NKEEP];   // 4096th largest (ascending pos 4096)

    const int i0 = tid * 8;
    float sc[8];
#pragma unroll
    for (int q = 0; q < 8; ++q) sc[q] = s[i0 + q];

    int sum_g = 0, sum_e = 0;
#pragma unroll
    for (int q = 0; q < 8; ++q) {
        sum_g += (sc[q] > T) ? 1 : 0;
        sum_e += (sc[q] == T) ? 1 : 0;
    }
    int tot_g, tot_e;
    (void)blk_excl_scan_1024(sum_g, tid, scan_lds, &tot_g);
    const int off_e = blk_excl_scan_1024(sum_e, tid, scan_lds, &tot_e);

    const int need = NKEEP - tot_g;     // how many ==T to keep (lowest index first)

    int keep[8];
    int sum_k = 0;
    int er = off_e;
#pragma unroll
    for (int q = 0; q < 8; ++q) {
        int kf = 0;
        if (sc[q] > T) kf = 1;
        else if (sc[q] == T) { kf = (er < need) ? 1 : 0; ++er; }
        keep[q] = kf;
        sum_k += kf;
    }
    int tot_k;
    int pos = blk_excl_scan_1024(sum_k, tid, scan_lds, &tot_k);

#pragma unroll
    for (int q = 0; q < 8; ++q) {
        mask_out[(size_t)b * NTOK + i0 + q] = keep[q] ? 1.0f : 0.0f;
        if (keep[q]) {
            idx_out[(size_t)b * NKEEP + pos] = i0 + q;
            ++pos;
        }
    }
}

// ---------------------------------------------------------------------------
// Kernel C: gather selected token rows. One block per (b, kpos): 1024 floats.
// ---------------------------------------------------------------------------
__global__ __launch_bounds__(256)
void dtr_gather_kernel(const float* __restrict__ tokens,
                       const int* __restrict__ idx,
                       float* __restrict__ selected)
{
    const int g    = blockIdx.x;        // 0 .. NB*NKEEP-1
    const int b    = g >> 12;           // / NKEEP
    const int src  = idx[g];
    const float4* sp = reinterpret_cast<const float4*>(
        tokens + ((size_t)b * NTOK + (size_t)src) * DIM);
    float4* dp = reinterpret_cast<float4*>(selected + (size_t)g * DIM);
    dp[threadIdx.x] = sp[threadIdx.x];
}

// ---------------------------------------------------------------------------
extern "C" void kernel_launch(void* const* d_in, const int* in_sizes, int n_in,
                              void* d_out, int out_size, void* d_ws, size_t ws_size,
                              hipStream_t stream)
{
    const float* tokens = (const float*)d_in[0];  // [4,8192,1024]
    const float* W1     = (const float*)d_in[1];  // [1024,512]
    const float* b1     = (const float*)d_in[2];  // [512]
    const float* W2     = (const float*)d_in[3];  // [512,1]
    const float* b2     = (const float*)d_in[4];  // [1]

    float* out      = (float*)d_out;
    float* selected = out;                                   // 4*4096*1024
    float* mask     = out + (size_t)NB * NKEEP * DIM;        // 4*8192

    float* scores = (float*)d_ws;                            // 32768 f32
    int*   idx    = (int*)((char*)d_ws + (size_t)NB * NTOK * sizeof(float));

    dtr_scores_kernel<<<(NB * NTOK) / TM, 512, 0, stream>>>(
        tokens, W1, b1, W2, b2, scores);
    dtr_topk_kernel<<<NB, 1024, 0, stream>>>(scores, idx, mask);
    dtr_gather_kernel<<<NB * NKEEP, 256, 0, stream>>>(tokens, idx, selected);
}